// Round 1
// baseline (307.971 us; speedup 1.0000x reference)
//
#include <hip/hip_runtime.h>
#include <hip/hip_cooperative_groups.h>
#include <hip/hip_bf16.h>
#include <math.h>

namespace cg = cooperative_groups;

// Chamfer distance via MFMA, fp16 quantized / fp32 accumulate.
// K-packing: A_row = (-2ax,-2ay,-2az, 1, sqa, 0,0,0), B_col = (bx,by,bz, sqb, 1, ...)
// => MFMA dot = sqa + sqb - 2 a.b = full squared distance (from quantized coords).
// R10 vs R9: all three dispatches fused into ONE cooperative kernel
// (pack -> grid.sync -> sweep -> grid.sync -> distributed reduce).
// Theory: timed region = 256MiB ws poison (~40us, fixed) + per-dispatch
// overhead (~8us x3) + ~13us device work; killing two dispatches is the
// only remaining lever (sweep inner loop is at the v_min3 VALU floor).
// Fallback to the proven 3-kernel chain if cooperative launch errors.

typedef _Float16 half8    __attribute__((ext_vector_type(8)));
typedef float    floatx16 __attribute__((ext_vector_type(16)));

constexpr int CH   = 4096;     // B points per block chunk (32 KB LDS)
constexpr int ROWS = 128;      // 4 waves * 32 rows
constexpr int BLK  = 256;

// ---- pack one point into an f16 fragment (x,y,z,|p|^2) ----
__device__ __forceinline__ uint2 pack_point(const float* __restrict__ P, int j)
{
    float x = P[3*j], y = P[3*j+1], z = P[3*j+2];
    _Float16 hx = (_Float16)x, hy = (_Float16)y, hz = (_Float16)z;
    float qx = (float)hx, qy = (float)hy, qz = (float)hz;
    _Float16 hw = (_Float16)(qx*qx + qy*qy + qz*qz);
    union { _Float16 h[4]; uint2 u; } p;
    p.h[0] = hx; p.h[1] = hy; p.h[2] = hz; p.h[3] = hw;
    return p.u;
}

// ---- the R9 sweep body, unchanged (shared by fused + fallback kernels) ----
__device__ __forceinline__ void sweep_body(
    const uint2* __restrict__ F1, const uint2* __restrict__ F2,
    float* __restrict__ part, int n1, int n2, int YC)
{
    __shared__ uint2 sB[CH];          // pre-packed fragments, straight copy
    __shared__ float sRowMin[ROWS];

    const int dir   = blockIdx.z;
    const uint2* FA = dir == 0 ? F1 : F2;
    const uint2* FB = dir == 0 ? F2 : F1;
    const int nA    = dir == 0 ? n1 : n2;
    float* pbase    = part + (dir == 0 ? 0 : (size_t)YC * n1);

    const int tid  = threadIdx.x;
    const int wave = tid >> 6;
    const int lane = tid & 63;
    const int n    = lane & 31;
    const int g    = lane >> 5;
    const bool g0  = (g == 0);

    // ---- stage: pure 32KB copy, 16B granules (no math, coalesced) ----
    {
        const uint4* src = (const uint4*)(FB + (size_t)blockIdx.y * CH);
        uint4* dst = (uint4*)sB;
        for (int i = tid; i < CH / 2; i += BLK) dst[i] = src[i];
    }

    // ---- A fragment: one 8B load + 3 f16 muls (exact *-2) ----
    const _Float16 h0 = (_Float16)0.0f;
    half8 af;
    {
        int arow = blockIdx.x * ROWS + wave * 32 + n;   // < NP by construction
        union { uint2 u; _Float16 h[4]; } au; au.u = FA[arow];
        const _Float16 m2 = (_Float16)(-2.0f);
        af[0] = g0 ? (_Float16)(au.h[0] * m2) : h0;
        af[1] = g0 ? (_Float16)(au.h[1] * m2) : h0;
        af[2] = g0 ? (_Float16)(au.h[2] * m2) : h0;
        af[3] = g0 ? (_Float16)1.0f : h0;
        af[4] = g0 ? au.h[3] : h0;
        af[5] = h0; af[6] = h0; af[7] = h0;
    }

    __syncthreads();

    floatx16 rowmin;
#pragma unroll
    for (int r = 0; r < 16; ++r) rowmin[r] = 1e30f;
    const floatx16 zacc = {};

    // Persistent B-operand quads: upper pair (1.0h,0 | 0,0) written ONCE;
    // per-iter ds_read_b64 lands directly in the lower pair.
    union BF { half8 v; unsigned u[4]; uint2 lo; };
    BF bu0, bu1, bu2, bu3;
    { union { _Float16 h[2]; unsigned u; } q;
      q.h[0] = (_Float16)1.0f; q.h[1] = h0;
      bu0.u[2] = q.u; bu0.u[3] = 0u;
      bu1.u[2] = q.u; bu1.u[3] = 0u;
      bu2.u[2] = q.u; bu2.u[3] = 0u;
      bu3.u[2] = q.u; bu3.u[3] = 0u; }

    // ---- main sweep: 4 B col-tiles (128 points) per iteration, 4 MFMAs ----
    for (int bt = 0; bt < CH / 128; ++bt) {
        const uint2* p = sB + bt * 128 + n;    // broadcast: g0/g1 read same addr
        bu0.lo = p[0];
        bu1.lo = p[32];
        bu2.lo = p[64];
        bu3.lo = p[96];

        floatx16 d0 = __builtin_amdgcn_mfma_f32_32x32x16_f16(af, bu0.v, zacc, 0, 0, 0);
        floatx16 d1 = __builtin_amdgcn_mfma_f32_32x32x16_f16(af, bu1.v, zacc, 0, 0, 0);
        floatx16 d2 = __builtin_amdgcn_mfma_f32_32x32x16_f16(af, bu2.v, zacc, 0, 0, 0);
        floatx16 d3 = __builtin_amdgcn_mfma_f32_32x32x16_f16(af, bu3.v, zacc, 0, 0, 0);

#pragma unroll
        for (int r = 0; r < 16; ++r) {
            float t = fminf(fminf(rowmin[r], d0[r]), d1[r]);     // v_min3
            rowmin[r] = fminf(fminf(t, d2[r]), d3[r]);           // v_min3
        }
    }

    // ---- epilogue: reduce across the 32 cols (xor-shuffle within n-group) ----
#pragma unroll
    for (int mask = 1; mask <= 16; mask <<= 1)
#pragma unroll
        for (int r = 0; r < 16; ++r)
            rowmin[r] = fminf(rowmin[r], __shfl_xor(rowmin[r], mask));

    if (n == 0) {
#pragma unroll
        for (int r = 0; r < 16; ++r) {
            int rr = wave * 32 + g * 4 + ((r & 3) + 8 * (r >> 2));   // C/D row map
            sRowMin[rr] = rowmin[r];
        }
    }
    __syncthreads();

    if (tid < ROWS) {   // one partial slot per (dir,row,ychunk) — no atomics
        int grow = blockIdx.x * ROWS + tid;
        if (grow < nA) pbase[(size_t)grow * YC + blockIdx.y] = sRowMin[tid];
    }
}

// ================= fused cooperative kernel (single dispatch) =================
__global__ __launch_bounds__(BLK, 4) void chamfer_fused_kernel(
    const float* __restrict__ P1, const float* __restrict__ P2,
    uint2* __restrict__ F1, uint2* __restrict__ F2,
    float* __restrict__ part, float* __restrict__ out,
    int n1, int n2, int YC, int NP)
{
    cg::grid_group gg = cg::this_grid();
    const int fb = blockIdx.x + gridDim.x * (blockIdx.y + gridDim.y * blockIdx.z);

    // ---- phase A: pack both clouds (262144 threads cover 2*NP = 32768) ----
    {
        int i = fb * BLK + threadIdx.x;
        if (i == 0) out[0] = 0.0f;                 // before any phase-C atomicAdd
        if (i < 2 * NP) {
            if (i < NP) { int j = i < n1 ? i : n1 - 1;            F1[i]      = pack_point(P1, j); }
            else        { int i2 = i - NP; int j = i2 < n2 ? i2 : n2 - 1; F2[i2] = pack_point(P2, j); }
        }
    }
    gg.sync();

    // ---- phase B: the proven R9 sweep ----
    sweep_body(F1, F2, part, n1, n2, YC);
    gg.sync();

    // ---- phase C: distributed reduce, 32 rows per block (1024 blk * 32 = 32768) ----
    {
        const int ntot = n1 + n2;
        if (threadIdx.x < 32) {
            int r = fb * 32 + threadIdx.x;
            float acc = 0.0f;
            if (r < ntot) {
                float m;
                if (YC == 4) {   // part is 16B-aligned, 4 floats per row
                    const float4 v = ((const float4*)part)[r];
                    m = fminf(fminf(v.x, v.y), fminf(v.z, v.w));
                } else {
                    const float* p = part + (size_t)r * YC;
                    m = 1e30f;
                    for (int y = 0; y < YC; ++y) m = fminf(m, p[y]);
                }
                acc = sqrtf(fmaxf(m, 0.0f));
            }
#pragma unroll
            for (int mask = 1; mask <= 16; mask <<= 1)
                acc += __shfl_xor(acc, mask, 32);
            if (threadIdx.x == 0) atomicAdd(out, acc);
        }
    }
}

// ================= fallback 3-kernel chain (R9, unchanged) =================
__global__ __launch_bounds__(256) void pack_kernel(
    const float* __restrict__ P1, const float* __restrict__ P2,
    uint2* __restrict__ F1, uint2* __restrict__ F2,
    int n1, int n2, int NP, float* __restrict__ out)
{
    int i = blockIdx.x * 256 + threadIdx.x;
    if (i == 0) out[0] = 0.0f;
    if (i < NP)          { int j = i < n1 ? i : n1 - 1;               F1[i]      = pack_point(P1, j); }
    else if (i < 2 * NP) { int i2 = i - NP; int j = i2 < n2 ? i2 : n2 - 1; F2[i2] = pack_point(P2, j); }
}

__global__ __launch_bounds__(BLK, 4) void chamfer_sweep_kernel(
    const uint2* __restrict__ F1, const uint2* __restrict__ F2,
    float* __restrict__ part, int n1, int n2, int YC)
{
    sweep_body(F1, F2, part, n1, n2, YC);
}

__global__ __launch_bounds__(256) void reduce_kernel(
    const float* __restrict__ part, float* __restrict__ out,
    int ntot, int YC)
{
    __shared__ float s[256];
    int r = blockIdx.x * 256 + threadIdx.x;
    float acc = 0.0f;
    if (r < ntot) {
        float m;
        if (YC == 4) {
            const float4 v = ((const float4*)part)[r];
            m = fminf(fminf(v.x, v.y), fminf(v.z, v.w));
        } else {
            const float* p = part + (size_t)r * YC;
            m = 1e30f;
            for (int y = 0; y < YC; ++y) m = fminf(m, p[y]);
        }
        acc = sqrtf(fmaxf(m, 0.0f));
    }
    s[threadIdx.x] = acc;
    __syncthreads();
    for (int w = 128; w > 0; w >>= 1) {
        if (threadIdx.x < w) s[threadIdx.x] += s[threadIdx.x + w];
        __syncthreads();
    }
    if (threadIdx.x == 0) atomicAdd(out, s[0]);
}

extern "C" void kernel_launch(void* const* d_in, const int* in_sizes, int n_in,
                              void* d_out, int out_size, void* d_ws, size_t ws_size,
                              hipStream_t stream) {
    const float* P1 = (const float*)d_in[0];
    const float* P2 = (const float*)d_in[1];
    const int n1 = in_sizes[0] / 3;   // 16384
    const int n2 = in_sizes[1] / 3;   // 16384
    const int nmax = (n1 > n2) ? n1 : n2;
    const int YC = (nmax + CH - 1) / CH;          // y-chunks (4)
    const int NP = YC * CH;                       // padded point count (16384)

    uint2* F1   = (uint2*)d_ws;                   // packed fragments, cloud 1
    uint2* F2   = F1 + NP;                        // packed fragments, cloud 2
    float* part = (float*)(F2 + NP);              // [(n1+n2) * YC] partial row-mins
    float* out  = (float*)d_out;

    dim3 grid(NP / ROWS, YC, 2);                  // 1024 blocks = exactly 4/CU

    void* args[] = { (void*)&P1, (void*)&P2, (void*)&F1, (void*)&F2,
                     (void*)&part, (void*)&out,
                     (void*)&n1, (void*)&n2, (void*)&YC, (void*)&NP };
    hipError_t err = hipLaunchCooperativeKernel(
        (void*)chamfer_fused_kernel, grid, dim3(BLK), args, 0, stream);

    if (err != hipSuccess) {
        // Hedge: eager fallback = the harness-verified R9 3-kernel chain.
        (void)hipGetLastError();
        pack_kernel<<<(2 * NP + 255) / 256, 256, 0, stream>>>(P1, P2, F1, F2, n1, n2, NP, out);
        chamfer_sweep_kernel<<<grid, BLK, 0, stream>>>(F1, F2, part, n1, n2, YC);
        reduce_kernel<<<(n1 + n2 + 255) / 256, 256, 0, stream>>>(part, out, n1 + n2, YC);
    }
}

// Round 2
// 103.937 us; speedup vs baseline: 2.9630x; 2.9630x over previous
//
#include <hip/hip_runtime.h>
#include <hip/hip_bf16.h>
#include <math.h>

// Chamfer distance via MFMA, fp16 quantized / fp32 accumulate.
// K-packing: A_row = (-2ax,-2ay,-2az, 1, sqa, 0,0,0), B_col = (bx,by,bz, sqb, 1, ...)
// => MFMA dot = sqa + sqb - 2 a.b = full squared distance (from quantized coords).
//
// R11 vs R9/R10: R10 proved grid.sync() costs ~100us/sync on MI355X (8 XCDs,
// device-scope fence) -- cooperative fusion abandoned. Instead the dispatch
// count drops 3 -> 2 with NO sync: each sweep block now stages the ENTIRE
// packed B cloud (16384 pts = 128 KB LDS, 1 block/CU, grid 256 = exactly
// 1/CU) and therefore computes FINAL row-mins for its 128 A-rows. The
// reduce kernel and the partials buffer are gone; the sweep epilogue does
// sqrt + block-sum + one atomicAdd. out=0 is written by the pack dispatch
// (stream order). Manual 1-iter-ahead B prefetch covers ds_read latency at
// 1 wave/SIMD (no co-resident waves to hide it anymore).

typedef _Float16 half8    __attribute__((ext_vector_type(8)));
typedef float    floatx16 __attribute__((ext_vector_type(16)));

constexpr int CHMAX = 16384;   // full padded B cloud per block (128 KB LDS)
constexpr int ROWS  = 128;     // 4 waves * 32 rows
constexpr int BLK   = 256;

// ---- pack one point into an f16 fragment (x,y,z,|p|^2) ----
__device__ __forceinline__ uint2 pack_point(const float* __restrict__ P, int j)
{
    float x = P[3*j], y = P[3*j+1], z = P[3*j+2];
    _Float16 hx = (_Float16)x, hy = (_Float16)y, hz = (_Float16)z;
    float qx = (float)hx, qy = (float)hy, qz = (float)hz;
    _Float16 hw = (_Float16)(qx*qx + qy*qy + qz*qz);
    union { _Float16 h[4]; uint2 u; } p;
    p.h[0] = hx; p.h[1] = hy; p.h[2] = hz; p.h[3] = hw;
    return p.u;
}

__global__ __launch_bounds__(256) void pack_kernel(
    const float* __restrict__ P1, const float* __restrict__ P2,
    uint2* __restrict__ F1, uint2* __restrict__ F2,
    int n1, int n2, int NP, float* __restrict__ out)
{
    int i = blockIdx.x * 256 + threadIdx.x;
    if (i == 0) out[0] = 0.0f;           // stream-ordered before sweep's atomics
    if (i < NP)          { int j = i < n1 ? i : n1 - 1;                    F1[i]  = pack_point(P1, j); }
    else if (i < 2 * NP) { int i2 = i - NP; int j = i2 < n2 ? i2 : n2 - 1; F2[i2] = pack_point(P2, j); }
}

// Fused sweep + reduce: each block owns 128 A-rows x the FULL B cloud.
__global__ __launch_bounds__(BLK) void chamfer_sweep_kernel(
    const uint2* __restrict__ F1, const uint2* __restrict__ F2,
    float* __restrict__ out, int n1, int n2, int NP)
{
    __shared__ uint2 sB[CHMAX];       // entire packed B cloud, straight copy
    __shared__ float sSum[8];         // one partial per (wave, g)

    const int dir   = blockIdx.z;
    const uint2* FA = dir == 0 ? F1 : F2;
    const uint2* FB = dir == 0 ? F2 : F1;
    const int nA    = dir == 0 ? n1 : n2;

    const int tid  = threadIdx.x;
    const int wave = tid >> 6;
    const int lane = tid & 63;
    const int n    = lane & 31;
    const int g    = lane >> 5;
    const bool g0  = (g == 0);

    // ---- stage: pure 128KB copy, 16B granules (no math, coalesced) ----
    {
        const uint4* src = (const uint4*)FB;
        uint4* dst = (uint4*)sB;
        for (int i = tid; i < NP / 2; i += BLK) dst[i] = src[i];
    }

    // ---- A fragment: one 8B load + 3 f16 muls (exact *-2) ----
    const _Float16 h0 = (_Float16)0.0f;
    half8 af;
    {
        int arow = blockIdx.x * ROWS + wave * 32 + n;   // < NP by construction
        union { uint2 u; _Float16 h[4]; } au; au.u = FA[arow];
        const _Float16 m2 = (_Float16)(-2.0f);
        af[0] = g0 ? (_Float16)(au.h[0] * m2) : h0;
        af[1] = g0 ? (_Float16)(au.h[1] * m2) : h0;
        af[2] = g0 ? (_Float16)(au.h[2] * m2) : h0;
        af[3] = g0 ? (_Float16)1.0f : h0;
        af[4] = g0 ? au.h[3] : h0;
        af[5] = h0; af[6] = h0; af[7] = h0;
    }

    __syncthreads();

    floatx16 rowmin;
#pragma unroll
    for (int r = 0; r < 16; ++r) rowmin[r] = 1e30f;
    const floatx16 zacc = {};

    // Persistent B-operand quads: upper pair (1.0h,0 | 0,0) written ONCE;
    // per-iter the prefetched uint2 lands in the lower pair.
    union BF { half8 v; unsigned u[4]; uint2 lo; };
    BF bu0, bu1, bu2, bu3;
    { union { _Float16 h[2]; unsigned u; } q;
      q.h[0] = (_Float16)1.0f; q.h[1] = h0;
      bu0.u[2] = q.u; bu0.u[3] = 0u;
      bu1.u[2] = q.u; bu1.u[3] = 0u;
      bu2.u[2] = q.u; bu2.u[3] = 0u;
      bu3.u[2] = q.u; bu3.u[3] = 0u; }

    // ---- main sweep: 4 B col-tiles (128 points) per iter, 4 MFMAs,
    //      1-iter-ahead register prefetch (only 1 wave/SIMD to hide ds lat) ----
    const int NT = NP / 128;
    const uint2* p0 = sB + n;                     // broadcast: g0/g1 same addr
    uint2 c0 = p0[0], c1 = p0[32], c2 = p0[64], c3 = p0[96];

    for (int bt = 0; bt < NT; ++bt) {
        const uint2* pn = sB + (bt + 1 < NT ? (bt + 1) * 128 : 0) + n;
        uint2 f0 = pn[0], f1 = pn[32], f2 = pn[64], f3 = pn[96];

        bu0.lo = c0;
        bu1.lo = c1;
        bu2.lo = c2;
        bu3.lo = c3;

        floatx16 d0 = __builtin_amdgcn_mfma_f32_32x32x16_f16(af, bu0.v, zacc, 0, 0, 0);
        floatx16 d1 = __builtin_amdgcn_mfma_f32_32x32x16_f16(af, bu1.v, zacc, 0, 0, 0);
        floatx16 d2 = __builtin_amdgcn_mfma_f32_32x32x16_f16(af, bu2.v, zacc, 0, 0, 0);
        floatx16 d3 = __builtin_amdgcn_mfma_f32_32x32x16_f16(af, bu3.v, zacc, 0, 0, 0);

#pragma unroll
        for (int r = 0; r < 16; ++r) {
            float t = fminf(fminf(rowmin[r], d0[r]), d1[r]);     // v_min3
            rowmin[r] = fminf(fminf(t, d2[r]), d3[r]);           // v_min3
        }

        c0 = f0; c1 = f1; c2 = f2; c3 = f3;
    }

    // ---- reduce across the 32 cols (xor-shuffle within n-group) ----
#pragma unroll
    for (int mask = 1; mask <= 16; mask <<= 1)
#pragma unroll
        for (int r = 0; r < 16; ++r)
            rowmin[r] = fminf(rowmin[r], __shfl_xor(rowmin[r], mask));

    // ---- epilogue: rows are FINAL mins now -> sqrt, block-sum, one atomic ----
    float acc = 0.0f;
    if (n == 0) {
#pragma unroll
        for (int r = 0; r < 16; ++r) {
            int grow = blockIdx.x * ROWS + wave * 32 + g * 4 + ((r & 3) + 8 * (r >> 2));
            if (grow < nA) acc += sqrtf(fmaxf(rowmin[r], 0.0f));
        }
        sSum[wave * 2 + g] = acc;
    }
    __syncthreads();

    if (tid == 0) {
        float s = 0.0f;
#pragma unroll
        for (int i = 0; i < 8; ++i) s += sSum[i];
        atomicAdd(out, s);
    }
}

extern "C" void kernel_launch(void* const* d_in, const int* in_sizes, int n_in,
                              void* d_out, int out_size, void* d_ws, size_t ws_size,
                              hipStream_t stream) {
    const float* P1 = (const float*)d_in[0];
    const float* P2 = (const float*)d_in[1];
    const int n1 = in_sizes[0] / 3;   // 16384
    const int n2 = in_sizes[1] / 3;   // 16384
    const int nmax = (n1 > n2) ? n1 : n2;
    int NP = ((nmax + 127) / 128) * 128;          // pad to MFMA tile multiple
    if (NP > CHMAX) NP = CHMAX;                   // problem is fixed at 16384
    const int NPp = NP;

    uint2* F1   = (uint2*)d_ws;                   // packed fragments, cloud 1
    uint2* F2   = F1 + NPp;                       // packed fragments, cloud 2
    float* out  = (float*)d_out;

    pack_kernel<<<(2 * NPp + 255) / 256, 256, 0, stream>>>(P1, P2, F1, F2, n1, n2, NPp, out);

    {   // 256 blocks = exactly 1/CU; each block: 128 A-rows x full B cloud
        dim3 grid(NPp / ROWS, 1, 2);
        chamfer_sweep_kernel<<<grid, BLK, 0, stream>>>(F1, F2, out, n1, n2, NPp);
    }
}

// Round 3
// 77.941 us; speedup vs baseline: 3.9513x; 1.3335x over previous
//
#include <hip/hip_runtime.h>
#include <math.h>

// Chamfer distance via MFMA, fp16 quantized / fp32 accumulate.
// K-packing: A_row = (-2ax,-2ay,-2az, 1, sqa, 0,0,0), B_col = (bx,by,bz, sqb, 1, 0,0,0)
// => MFMA dot = sqa + sqb - 2 a.b = full squared distance (from quantized coords).
//
// R12 vs R11: R11 proved full-B-in-LDS at BLK=256 starves the SIMDs
// (1 wave/SIMD -> latency-bound, sweep 60us, Occ 10%). Fix: BLK=1024
// (16 waves = 4/SIMD, same as R9's winning occupancy), waves split as
// 4 row-groups x 4 B-quarters; per-wave loop shape identical to R9
// (32 iters x 4 MFMA), cross-wave min via 2KB LDS. Pack is folded in:
// each block packs the L2-resident B cloud directly into LDS and its own
// 128 A-rows in registers -- pack kernel + F1/F2 workspace round-trip gone.
// out=0 via 4-byte hipMemsetAsync (capture-safe). Total: 2 dispatches,
// no grid sync (R10 showed grid.sync costs ~100us on 8-XCD MI355X).

typedef _Float16 half8    __attribute__((ext_vector_type(8)));
typedef float    floatx16 __attribute__((ext_vector_type(16)));

constexpr int NPTS = 16384;    // max padded cloud size (128 KB LDS)
constexpr int ROWS = 128;      // A-rows per block (4 row-groups * 32)
constexpr int BLK  = 1024;     // 16 waves = 4/SIMD at 1 block/CU

// ---- pack one point into an f16 fragment (x,y,z,|p|^2) ----
__device__ __forceinline__ uint2 pack_point(const float* __restrict__ P, int j)
{
    float x = P[3*j], y = P[3*j+1], z = P[3*j+2];
    _Float16 hx = (_Float16)x, hy = (_Float16)y, hz = (_Float16)z;
    float qx = (float)hx, qy = (float)hy, qz = (float)hz;
    _Float16 hw = (_Float16)(qx*qx + qy*qy + qz*qz);
    union { _Float16 h[4]; uint2 u; } p;
    p.h[0] = hx; p.h[1] = hy; p.h[2] = hz; p.h[3] = hw;
    return p.u;
}

// One fused kernel: pack B->LDS, pack own A-rows->regs, sweep, reduce, atomicAdd.
__global__ __launch_bounds__(BLK, 4) void chamfer_all_kernel(
    const float* __restrict__ P1, const float* __restrict__ P2,
    float* __restrict__ out, int n1, int n2, int NP)
{
    __shared__ uint2 sB[NPTS];            // packed B cloud
    __shared__ float sRowMin[4][ROWS];    // per-B-quarter row mins
    __shared__ float sRed[ROWS];          // final per-row sqrt'd values

    const int dir   = blockIdx.z;
    const float* PA = dir == 0 ? P1 : P2;
    const float* PB = dir == 0 ? P2 : P1;
    const int nA    = dir == 0 ? n1 : n2;
    const int nB    = dir == 0 ? n2 : n1;

    const int tid  = threadIdx.x;
    const int wave = tid >> 6;
    const int lane = tid & 63;
    const int n    = lane & 31;
    const int g    = lane >> 5;
    const bool g0  = (g == 0);
    const int wr   = wave & 3;        // row-group: rows wr*32 .. wr*32+31
    const int wq   = wave >> 2;       // B-quarter index

    // ---- pack the FULL B cloud into LDS (reads are L2-resident, 192 KB) ----
    for (int j = tid; j < NP; j += BLK) {
        int jj = j < nB ? j : nB - 1;        // pad with dup of last point
        sB[j] = pack_point(PB, jj);
    }

    // ---- A fragment: pack own row directly from fp32 points ----
    const _Float16 h0 = (_Float16)0.0f;
    half8 af;
    {
        int arow = blockIdx.x * ROWS + wr * 32 + n;
        int j = arow < nA ? arow : nA - 1;
        union { uint2 u; _Float16 h[4]; } au; au.u = pack_point(PA, j);
        const _Float16 m2 = (_Float16)(-2.0f);
        af[0] = g0 ? (_Float16)(au.h[0] * m2) : h0;
        af[1] = g0 ? (_Float16)(au.h[1] * m2) : h0;
        af[2] = g0 ? (_Float16)(au.h[2] * m2) : h0;
        af[3] = g0 ? (_Float16)1.0f : h0;
        af[4] = g0 ? au.h[3] : h0;
        af[5] = h0; af[6] = h0; af[7] = h0;
    }

    __syncthreads();

    floatx16 rowmin;
#pragma unroll
    for (int r = 0; r < 16; ++r) rowmin[r] = 1e30f;
    const floatx16 zacc = {};

    // Persistent B-operand quads: upper pair (1.0h,0 | 0,0) written ONCE;
    // per-iter ds_read_b64 lands directly in the lower pair.
    union BF { half8 v; unsigned u[4]; uint2 lo; };
    BF bu0, bu1, bu2, bu3;
    { union { _Float16 h[2]; unsigned u; } q;
      q.h[0] = (_Float16)1.0f; q.h[1] = h0;
      bu0.u[2] = q.u; bu0.u[3] = 0u;
      bu1.u[2] = q.u; bu1.u[3] = 0u;
      bu2.u[2] = q.u; bu2.u[3] = 0u;
      bu3.u[2] = q.u; bu3.u[3] = 0u; }

    // ---- sweep own B-quarter: 32 iters x (4 ds_read_b64 + 4 MFMA + 8 min3),
    //      4 waves/SIMD provide the latency hiding (R9's proven regime) ----
    const int qlen = NP >> 2;                  // 4096 (NP padded to 512)
    const uint2* qbase = sB + wq * qlen + n;   // g0/g1 broadcast same addr
    for (int bt = 0; bt < qlen / 128; ++bt) {
        const uint2* p = qbase + bt * 128;
        bu0.lo = p[0];
        bu1.lo = p[32];
        bu2.lo = p[64];
        bu3.lo = p[96];

        floatx16 d0 = __builtin_amdgcn_mfma_f32_32x32x16_f16(af, bu0.v, zacc, 0, 0, 0);
        floatx16 d1 = __builtin_amdgcn_mfma_f32_32x32x16_f16(af, bu1.v, zacc, 0, 0, 0);
        floatx16 d2 = __builtin_amdgcn_mfma_f32_32x32x16_f16(af, bu2.v, zacc, 0, 0, 0);
        floatx16 d3 = __builtin_amdgcn_mfma_f32_32x32x16_f16(af, bu3.v, zacc, 0, 0, 0);

#pragma unroll
        for (int r = 0; r < 16; ++r) {
            float t = fminf(fminf(rowmin[r], d0[r]), d1[r]);     // v_min3
            rowmin[r] = fminf(fminf(t, d2[r]), d3[r]);           // v_min3
        }
    }

    // ---- reduce across the 32 cols (xor-shuffle within n-group) ----
#pragma unroll
    for (int mask = 1; mask <= 16; mask <<= 1)
#pragma unroll
        for (int r = 0; r < 16; ++r)
            rowmin[r] = fminf(rowmin[r], __shfl_xor(rowmin[r], mask));

    if (n == 0) {
#pragma unroll
        for (int r = 0; r < 16; ++r) {
            int rr = wr * 32 + g * 4 + ((r & 3) + 8 * (r >> 2));   // C/D row map
            sRowMin[wq][rr] = rowmin[r];
        }
    }
    __syncthreads();

    // ---- combine quarters, sqrt, block-sum, one atomicAdd ----
    if (tid < ROWS) {
        float m = fminf(fminf(sRowMin[0][tid], sRowMin[1][tid]),
                        fminf(sRowMin[2][tid], sRowMin[3][tid]));
        int grow = blockIdx.x * ROWS + tid;
        sRed[tid] = (grow < nA) ? sqrtf(fmaxf(m, 0.0f)) : 0.0f;
    }
    __syncthreads();

    if (tid < 64) {
        float v = sRed[tid] + sRed[tid + 64];
#pragma unroll
        for (int mask = 1; mask <= 32; mask <<= 1)
            v += __shfl_xor(v, mask);
        if (tid == 0) atomicAdd(out, v);
    }
}

extern "C" void kernel_launch(void* const* d_in, const int* in_sizes, int n_in,
                              void* d_out, int out_size, void* d_ws, size_t ws_size,
                              hipStream_t stream) {
    const float* P1 = (const float*)d_in[0];
    const float* P2 = (const float*)d_in[1];
    const int n1 = in_sizes[0] / 3;   // 16384
    const int n2 = in_sizes[1] / 3;   // 16384
    const int nmax = (n1 > n2) ? n1 : n2;
    int NP = ((nmax + 511) / 512) * 512;          // quarters stay 128-multiples
    if (NP > NPTS) NP = NPTS;                     // problem is fixed at 16384
    float* out = (float*)d_out;

    hipMemsetAsync(out, 0, sizeof(float), stream);   // capture-safe (harness uses memset fills)

    dim3 grid(NP / ROWS, 1, 2);                   // 256 blocks = exactly 1/CU
    chamfer_all_kernel<<<grid, BLK, 0, stream>>>(P1, P2, out, n1, n2, NP);
}